// Round 2
// baseline (431784.814 us; speedup 1.0000x reference)
//
#include <hip/hip_runtime.h>
#include <hip/hip_bf16.h>

#define T_SEQ 500000
#define NVOCAB 20
#define NEMBED 30
#define NH1 40
#define NH2 50
#define NG1 (4*NH1)   // 160
#define NG2 (4*NH2)   // 200
#define NTHREADS 448

// dtype-agnostic weight load: harness may deliver floats as f32 or bf16
__device__ __forceinline__ float ldw(const void* p, int i, int isf32) {
    if (isf32) return ((const float*)p)[i];
    return __bfloat162float(((const __hip_bfloat16*)p)[i]);
}

__global__ __launch_bounds__(NTHREADS, 1)
void lstm_seq(const int* __restrict__ tokens,
              const void* __restrict__ embed_w,
              const void* __restrict__ w_ih1,
              const void* __restrict__ w_hh1,
              const void* __restrict__ b_ih1,
              const void* __restrict__ b_hh1,
              const void* __restrict__ w_ih2,
              const void* __restrict__ w_hh2,
              const void* __restrict__ b_ih2,
              const void* __restrict__ b_hh2,
              const void* __restrict__ lin_w,
              const void* __restrict__ lin_b,
              void* __restrict__ out)
{
    __shared__ float G1[NVOCAB * NG1];   // 12.8 KB: token -> gate1 pre-activation
    __shared__ float h1s[2][64];         // double-buffered h1 (zeros beyond NH1)
    __shared__ float h2s[2][64];         // double-buffered h2

    const int tid  = threadIdx.x;
    const int lane = tid & 63;
    const int base = lane & 56;          // 8-lane group base within wave

    // ---- dtype sniff (uniform, deterministic): bf16 0.1*N(0,1) data never has
    // exponent-field >= 130 (|x|>=4); f32 mantissa halves read as bf16 do, w.p. ~0.5/word.
    int wild = 0;
    {
        const unsigned short* ew = (const unsigned short*)embed_w;
        #pragma unroll
        for (int i = 0; i < 64; ++i) {
            int ex = (ew[i] >> 7) & 0xFF;
            wild += (ex >= 130);
        }
    }
    const int isf32 = (wild > 0) ? 1 : 0;

    // ---------------- prologue ----------------
    for (int idx = tid; idx < NVOCAB * NG1; idx += NTHREADS) {
        int v = idx / NG1;
        int j = idx - v * NG1;
        float acc = ldw(b_ih1, j, isf32) + ldw(b_hh1, j, isf32);
        for (int e = 0; e < NEMBED; ++e)
            acc += ldw(embed_w, v*NEMBED + e, isf32) * ldw(w_ih1, j*NEMBED + e, isf32);
        G1[v*NG1 + j] = acc;
    }
    if (tid < 64) {
        h1s[0][tid] = 0.f; h1s[1][tid] = 0.f;
        h2s[0][tid] = 0.f; h2s[1][tid] = 0.f;
    }

    // roles: 8-lane group per state element k; 2 lanes per gate (i,f,g,o)
    const int grp  = tid >> 3;
    const int gt   = (tid >> 1) & 3;  // 0=i 1=f 2=g 3=o
    const int half = tid & 1;

    const bool p1 = (tid < 8*NH1);              // 320 threads: layer-1 gates
    const bool p2 = (tid < 8*NH2);              // 400 threads: layer-2 gates
    const bool pr = (tid >= 400 && tid < 440);  // 40 threads: output projection
    const int  pv = (tid - 400) >> 1;

    float w1[20];      // layer-1 recurrent weights (half a row)
    float c1 = 0.f;
    if (p1) {
        int j = gt*NH1 + grp;
        #pragma unroll
        for (int i = 0; i < 20; ++i) w1[i] = ldw(w_hh1, j*NH1 + half*20 + i, isf32);
    }

    float w2[50];      // layer-2: half0 = W_ih2 row (40, zero-pad), half1 = W_hh2 row
    float b2 = 0.f, c2 = 0.f;
    if (p2) {
        int j = gt*NH2 + grp;
        b2 = ldw(b_ih2, j, isf32) + ldw(b_hh2, j, isf32);
        if (half == 0) {
            #pragma unroll
            for (int i = 0; i < 40; ++i) w2[i] = ldw(w_ih2, j*NH1 + i, isf32);
            #pragma unroll
            for (int i = 40; i < 50; ++i) w2[i] = 0.f;
        } else {
            #pragma unroll
            for (int i = 0; i < 50; ++i) w2[i] = ldw(w_hh2, j*NH2 + i, isf32);
        }
    }

    float lw[25]; float lb = 0.f;   // projection weights (half a row)
    if (pr) {
        #pragma unroll
        for (int i = 0; i < 25; ++i) lw[i] = ldw(lin_w, pv*NH2 + half*25 + i, isf32);
        lb = ldw(lin_b, pv, isf32);
    }

    // branch-free activation: i,f,o -> sigmoid; g -> tanh = 2*sig(2x)-1
    const float xsc  = (gt == 2) ? 2.f : 1.f;
    const float rmul = (gt == 2) ? 2.f : 1.f;
    const float radd = (gt == 2) ? -1.f : 0.f;

    __hip_bfloat16* out_bf = (__hip_bfloat16*)out;
    float*          out_f  = (float*)out;

    __syncthreads();

    int tok = tokens[0];
    int p = 0;
    for (int t = 0; t < T_SEQ; ++t) {
        int tnIdx = t + 1 < T_SEQ ? t + 1 : T_SEQ - 1;
        int tok_next = tokens[tnIdx];   // prefetch

        // ---- phase 1: layer-1 gates + state; projection of step t-1 ----
        if (p1) {
            const float* hv = &h1s[p][half*20];
            float a0=0.f, a1=0.f, a2=0.f, a3=0.f;     // 4-way split dep chain
            #pragma unroll
            for (int i = 0; i < 20; i += 4) {
                a0 = fmaf(w1[i+0], hv[i+0], a0);
                a1 = fmaf(w1[i+1], hv[i+1], a1);
                a2 = fmaf(w1[i+2], hv[i+2], a2);
                a3 = fmaf(w1[i+3], hv[i+3], a3);
            }
            float acc = (a0+a1) + (a2+a3);
            acc += __shfl_xor(acc, 1);
            acc += G1[tok*NG1 + gt*NH1 + grp];
            float e = __expf(-acc * xsc);
            float r = __builtin_amdgcn_rcpf(1.f + e);
            float a = fmaf(r, rmul, radd);
            float vi = __shfl(a, base + 0);
            float vf = __shfl(a, base + 2);
            float vg = __shfl(a, base + 4);
            float vo = __shfl(a, base + 6);
            float cn = fmaf(vf, c1, vi * vg);
            c1 = cn;
            float e2 = __expf(-2.f * cn);
            float th = fmaf(2.f, __builtin_amdgcn_rcpf(1.f + e2), -1.f);
            if ((tid & 7) == 0) h1s[p^1][grp] = vo * th;
        }
        if (pr && t > 0) {
            const float* hv = &h2s[p][half*25];   // h2_{t-1}
            float a0=0.f, a1=0.f, a2=0.f, a3=0.f, a4=0.f;
            #pragma unroll
            for (int i = 0; i < 25; i += 5) {
                a0 = fmaf(lw[i+0], hv[i+0], a0);
                a1 = fmaf(lw[i+1], hv[i+1], a1);
                a2 = fmaf(lw[i+2], hv[i+2], a2);
                a3 = fmaf(lw[i+3], hv[i+3], a3);
                a4 = fmaf(lw[i+4], hv[i+4], a4);
            }
            float acc = ((a0+a1) + (a2+a3)) + a4;
            acc += __shfl_xor(acc, 1);
            if (half == 0) {
                float v = acc + lb;
                size_t idx = (size_t)(t-1)*NVOCAB + pv;
                if (isf32) out_f[idx] = v; else out_bf[idx] = __float2bfloat16(v);
            }
        }
        __syncthreads();

        // ---- phase 2: layer-2 gates + state ----
        if (p2) {
            const float* hv = half ? &h2s[p][0] : &h1s[p^1][0];
            float a0=0.f, a1=0.f, a2=0.f, a3=0.f, a4=0.f;
            #pragma unroll
            for (int i = 0; i < 50; i += 5) {
                a0 = fmaf(w2[i+0], hv[i+0], a0);
                a1 = fmaf(w2[i+1], hv[i+1], a1);
                a2 = fmaf(w2[i+2], hv[i+2], a2);
                a3 = fmaf(w2[i+3], hv[i+3], a3);
                a4 = fmaf(w2[i+4], hv[i+4], a4);
            }
            float acc = ((a0+a1) + (a2+a3)) + a4;
            acc += __shfl_xor(acc, 1);
            acc += b2;
            float e = __expf(-acc * xsc);
            float r = __builtin_amdgcn_rcpf(1.f + e);
            float a = fmaf(r, rmul, radd);
            float vi = __shfl(a, base + 0);
            float vf = __shfl(a, base + 2);
            float vg = __shfl(a, base + 4);
            float vo = __shfl(a, base + 6);
            float cn = fmaf(vf, c2, vi * vg);
            c2 = cn;
            float e2 = __expf(-2.f * cn);
            float th = fmaf(2.f, __builtin_amdgcn_rcpf(1.f + e2), -1.f);
            if ((tid & 7) == 0) h2s[p^1][grp] = vo * th;
        }
        __syncthreads();

        tok = tok_next;
        p ^= 1;
    }

    // epilogue: projection of final step
    if (pr) {
        const int pf = ((T_SEQ-1) & 1) ^ 1;
        const float* hv = &h2s[pf][half*25];
        float acc = 0.f;
        #pragma unroll
        for (int i = 0; i < 25; ++i) acc = fmaf(lw[i], hv[i], acc);
        acc += __shfl_xor(acc, 1);
        if (half == 0) {
            float v = acc + lb;
            size_t idx = (size_t)(T_SEQ-1)*NVOCAB + pv;
            if (isf32) out_f[idx] = v; else out_bf[idx] = __float2bfloat16(v);
        }
    }
}

extern "C" void kernel_launch(void* const* d_in, const int* in_sizes, int n_in,
                              void* d_out, int out_size, void* d_ws, size_t ws_size,
                              hipStream_t stream) {
    const int* tokens = (const int*)d_in[0];
    lstm_seq<<<dim3(1), dim3(NTHREADS), 0, stream>>>(
        tokens, d_in[1], d_in[2], d_in[3], d_in[4], d_in[5],
        d_in[6], d_in[7], d_in[8], d_in[9], d_in[10], d_in[11], d_out);
}

// Round 3
// 335229.883 us; speedup vs baseline: 1.2880x; 1.2880x over previous
//
#include <hip/hip_runtime.h>
#include <hip/hip_bf16.h>

#define T_SEQ 500000
#define NVOCAB 20
#define NEMBED 30
#define NH1 40
#define NH2 50
#define NG1 (4*NH1)   // 160
#define NTHREADS 256

// dtype-agnostic weight load: harness may deliver floats as f32 or bf16
__device__ __forceinline__ float ldw(const void* p, int i, int isf32) {
    if (isf32) return ((const float*)p)[i];
    return __bfloat162float(((const __hip_bfloat16*)p)[i]);
}

// quad_perm [1,0,3,2]: swap adjacent lane pairs — VALU (DPP), not LDS
__device__ __forceinline__ float qswap1(float v) {
    int r = __builtin_amdgcn_update_dpp(0, __float_as_int(v), 0xB1, 0xF, 0xF, true);
    return __int_as_float(r);
}

__global__ __launch_bounds__(NTHREADS, 1)
void lstm_seq(const int* __restrict__ tokens,
              const void* __restrict__ embed_w,
              const void* __restrict__ w_ih1,
              const void* __restrict__ w_hh1,
              const void* __restrict__ b_ih1,
              const void* __restrict__ b_hh1,
              const void* __restrict__ w_ih2,
              const void* __restrict__ w_hh2,
              const void* __restrict__ b_ih2,
              const void* __restrict__ b_hh2,
              const void* __restrict__ lin_w,
              const void* __restrict__ lin_b,
              void* __restrict__ out)
{
    // G1v4[v*40+k] = float4(pre_i, pre_f, pre_g, pre_o) for state k, token v
    __shared__ float4 G1v4[NVOCAB * NH1];   // 12.8 KB
    __shared__ float4 h1v4[2][12];          // h1 double-buffered, 48 floats (40 + pad)
    __shared__ float4 h2v4[2][14];          // h2 double-buffered, 56 floats (50 + pad)

    const int tid  = threadIdx.x;
    const int wv   = tid >> 6;      // wave: 0=L1, 1/2=L2, 3=proj
    const int lane = tid & 63;

    // ---- dtype sniff (uniform, deterministic) ----
    int wild = 0;
    {
        const unsigned short* ew = (const unsigned short*)embed_w;
        #pragma unroll
        for (int i = 0; i < 64; ++i) {
            int ex = (ew[i] >> 7) & 0xFF;
            wild += (ex >= 130);
        }
    }
    const int isf32 = (wild > 0) ? 1 : 0;

    // ---------------- prologue: G1 table + zero h buffers ----------------
    for (int idx = tid; idx < NVOCAB * NG1; idx += NTHREADS) {
        int v   = idx / NG1;
        int rem = idx - v * NG1;
        int k   = rem >> 2;
        int g   = rem & 3;
        int row = g * NH1 + k;
        float acc = ldw(b_ih1, row, isf32) + ldw(b_hh1, row, isf32);
        for (int e = 0; e < NEMBED; ++e)
            acc += ldw(embed_w, v*NEMBED + e, isf32) * ldw(w_ih1, row*NEMBED + e, isf32);
        ((float*)G1v4)[idx] = acc;
    }
    if (tid < 52) {
        float4 z = make_float4(0.f, 0.f, 0.f, 0.f);
        if (tid < 24) h1v4[tid / 12][tid % 12] = z;
        else {
            int t = tid - 24;
            h2v4[t / 14][t % 14] = z;
        }
    }

    // ---------------- per-role weight registers (overlaid layouts) ----------------
    // W0 (wv0, lane<40): wreg[g*40+j] = w_hh1[(g*40+lane)*40+j]
    // W1/W2 (pair per state): wreg[0..39]=wihA, [40..91]=whhA(pad0), [92..131]=wihB, [132..183]=whhB(pad0)
    // W3 (lane<20): wreg[0..51] = lin_w row (pad 0)
    float wreg[184];
    float c1 = 0.f, c2 = 0.f;
    float bA = 0.f, bB = 0.f, lb = 0.f;
    int   tok = 0;

    const int idx2 = ((wv - 1) << 5) + (lane >> 1);   // layer-2 state index
    const int r    = lane & 1;                        // 0: gates i,f   1: gates g,o
    const bool act2 = (wv == 1 || wv == 2) && idx2 < NH2;

    if (wv == 0) {
        if (lane < NH1) {
            #pragma unroll
            for (int g = 0; g < 4; ++g)
                #pragma unroll
                for (int j = 0; j < NH1; ++j)
                    wreg[g*40 + j] = ldw(w_hh1, (g*NH1 + lane)*NH1 + j, isf32);
        }
        tok = tokens[0];
    } else if (wv < 3) {
        if (act2) {
            int s = idx2;
            int rowA = (r ? 2*NH2 : 0) + s;       // i or g
            int rowB = (r ? 3*NH2 : NH2) + s;     // f or o
            #pragma unroll
            for (int k = 0; k < NH1; ++k) {
                wreg[k]      = ldw(w_ih2, rowA*NH1 + k, isf32);
                wreg[92 + k] = ldw(w_ih2, rowB*NH1 + k, isf32);
            }
            #pragma unroll
            for (int k = 0; k < NH2; ++k) {
                wreg[40 + k]  = ldw(w_hh2, rowA*NH2 + k, isf32);
                wreg[132 + k] = ldw(w_hh2, rowB*NH2 + k, isf32);
            }
            wreg[90] = wreg[91] = wreg[182] = wreg[183] = 0.f;
            bA = ldw(b_ih2, rowA, isf32) + ldw(b_hh2, rowA, isf32);
            bB = ldw(b_ih2, rowB, isf32) + ldw(b_hh2, rowB, isf32);
        }
    } else {
        if (lane < NVOCAB) {
            #pragma unroll
            for (int k = 0; k < NH2; ++k)
                wreg[k] = ldw(lin_w, lane*NH2 + k, isf32);
            wreg[50] = wreg[51] = 0.f;
            lb = ldw(lin_b, lane, isf32);
        }
    }

    // activation params for layer-2 gate A (r=0: sigmoid, r=1: tanh)
    const float xscA  = r ? 2.f : 1.f;
    const float rmulA = r ? 2.f : 1.f;
    const float raddA = r ? -1.f : 0.f;

    __hip_bfloat16* out_bf = (__hip_bfloat16*)out;
    float*          out_f  = (float*)out;

    __syncthreads();

    // ---------------- pipelined main loop: one barrier per step ----------------
    // iter u: W0 -> h1[u];  W1/W2 -> h2[u-1];  W3 -> out[u-2]
    for (int u = 0; u < T_SEQ + 2; ++u) {
        const int cur = u & 1, prv = cur ^ 1;

        if (wv == 0) {
            if (u < T_SEQ) {
                int tn = tokens[(u + 1 < T_SEQ) ? (u + 1) : (T_SEQ - 1)];
                if (lane < NH1) {
                    float4 g4 = G1v4[tok*NH1 + lane];
                    float a0 = g4.x, a1 = g4.y, a2 = g4.z, a3 = g4.w;
                    #pragma unroll
                    for (int c = 0; c < 10; ++c) {
                        float4 hv = h1v4[prv][c];
                        a0 = fmaf(wreg[  0 + c*4+0], hv.x, a0); a0 = fmaf(wreg[  0 + c*4+1], hv.y, a0);
                        a0 = fmaf(wreg[  0 + c*4+2], hv.z, a0); a0 = fmaf(wreg[  0 + c*4+3], hv.w, a0);
                        a1 = fmaf(wreg[ 40 + c*4+0], hv.x, a1); a1 = fmaf(wreg[ 40 + c*4+1], hv.y, a1);
                        a1 = fmaf(wreg[ 40 + c*4+2], hv.z, a1); a1 = fmaf(wreg[ 40 + c*4+3], hv.w, a1);
                        a2 = fmaf(wreg[ 80 + c*4+0], hv.x, a2); a2 = fmaf(wreg[ 80 + c*4+1], hv.y, a2);
                        a2 = fmaf(wreg[ 80 + c*4+2], hv.z, a2); a2 = fmaf(wreg[ 80 + c*4+3], hv.w, a2);
                        a3 = fmaf(wreg[120 + c*4+0], hv.x, a3); a3 = fmaf(wreg[120 + c*4+1], hv.y, a3);
                        a3 = fmaf(wreg[120 + c*4+2], hv.z, a3); a3 = fmaf(wreg[120 + c*4+3], hv.w, a3);
                    }
                    float aI = __builtin_amdgcn_rcpf(1.f + __expf(-a0));
                    float aF = __builtin_amdgcn_rcpf(1.f + __expf(-a1));
                    float aG = fmaf(2.f, __builtin_amdgcn_rcpf(1.f + __expf(-2.f*a2)), -1.f);
                    float aO = __builtin_amdgcn_rcpf(1.f + __expf(-a3));
                    float cn = fmaf(aF, c1, aI * aG);
                    c1 = cn;
                    float th = fmaf(2.f, __builtin_amdgcn_rcpf(1.f + __expf(-2.f*cn)), -1.f);
                    ((float*)&h1v4[cur][0])[lane] = aO * th;
                }
                tok = tn;
            }
        } else if (wv < 3) {
            if (u >= 1 && u <= T_SEQ && act2) {
                float accA = bA, accB = bB;
                #pragma unroll
                for (int c = 0; c < 10; ++c) {          // x-part: h1[u-1]
                    float4 hv = h1v4[prv][c];
                    accA = fmaf(wreg[     c*4+0], hv.x, accA); accA = fmaf(wreg[     c*4+1], hv.y, accA);
                    accA = fmaf(wreg[     c*4+2], hv.z, accA); accA = fmaf(wreg[     c*4+3], hv.w, accA);
                    accB = fmaf(wreg[92 + c*4+0], hv.x, accB); accB = fmaf(wreg[92 + c*4+1], hv.y, accB);
                    accB = fmaf(wreg[92 + c*4+2], hv.z, accB); accB = fmaf(wreg[92 + c*4+3], hv.w, accB);
                }
                #pragma unroll
                for (int c = 0; c < 13; ++c) {          // h-part: h2[u-2]
                    float4 hv = h2v4[cur][c];
                    accA = fmaf(wreg[ 40 + c*4+0], hv.x, accA); accA = fmaf(wreg[ 40 + c*4+1], hv.y, accA);
                    accA = fmaf(wreg[ 40 + c*4+2], hv.z, accA); accA = fmaf(wreg[ 40 + c*4+3], hv.w, accA);
                    accB = fmaf(wreg[132 + c*4+0], hv.x, accB); accB = fmaf(wreg[132 + c*4+1], hv.y, accB);
                    accB = fmaf(wreg[132 + c*4+2], hv.z, accB); accB = fmaf(wreg[132 + c*4+3], hv.w, accB);
                }
                // r=0: aA=sig(i), aB=sig(f);  r=1: aA=tanh(g), aB=sig(o)
                float aA = fmaf(__builtin_amdgcn_rcpf(1.f + __expf(-accA * xscA)), rmulA, raddA);
                float aB = __builtin_amdgcn_rcpf(1.f + __expf(-accB));
                float sA = qswap1(aA);   // r=0 receives tanh(g)
                float sB = qswap1(aB);   // r=0 receives sig(o)
                float cn = fmaf(aB, c2, aA * sA);
                c2 = cn;
                float th = fmaf(2.f, __builtin_amdgcn_rcpf(1.f + __expf(-2.f*cn)), -1.f);
                if (r == 0) ((float*)&h2v4[prv][0])[idx2] = sB * th;
            }
        } else {
            if (u >= 2 && lane < NVOCAB) {
                float a0 = 0.f, a1 = 0.f, a2 = 0.f, a3 = 0.f;
                #pragma unroll
                for (int c = 0; c < 13; ++c) {          // h2[u-2]
                    float4 hv = h2v4[cur][c];
                    a0 = fmaf(wreg[c*4+0], hv.x, a0);
                    a1 = fmaf(wreg[c*4+1], hv.y, a1);
                    a2 = fmaf(wreg[c*4+2], hv.z, a2);
                    a3 = fmaf(wreg[c*4+3], hv.w, a3);
                }
                float v = ((a0 + a1) + (a2 + a3)) + lb;
                size_t oi = (size_t)(u - 2) * NVOCAB + lane;
                if (isf32) out_f[oi] = v; else out_bf[oi] = __float2bfloat16(v);
            }
        }

        __syncthreads();
    }
}

extern "C" void kernel_launch(void* const* d_in, const int* in_sizes, int n_in,
                              void* d_out, int out_size, void* d_ws, size_t ws_size,
                              hipStream_t stream) {
    const int* tokens = (const int*)d_in[0];
    lstm_seq<<<dim3(1), dim3(NTHREADS), 0, stream>>>(
        tokens, d_in[1], d_in[2], d_in[3], d_in[4], d_in[5],
        d_in[6], d_in[7], d_in[8], d_in[9], d_in[10], d_in[11], d_out);
}

// Round 4
// 265625.146 us; speedup vs baseline: 1.6255x; 1.2620x over previous
//
#include <hip/hip_runtime.h>
#include <hip/hip_bf16.h>

#define T_SEQ 500000
#define NVOCAB 20
#define NEMBED 30
#define NH1 40
#define NH2 50
#define NTHREADS 512

typedef float v2f __attribute__((ext_vector_type(2)));
typedef float v4f __attribute__((ext_vector_type(4)));

// dtype-agnostic weight load: harness may deliver floats as f32 or bf16
__device__ __forceinline__ float ldw(const void* p, int i, int isf32) {
    if (isf32) return ((const float*)p)[i];
    return __bfloat162float(((const __hip_bfloat16*)p)[i]);
}

__device__ __forceinline__ v2f mk2(float a, float b) { v2f r; r[0] = a; r[1] = b; return r; }

// DPP quad_perm swaps (VALU pipe, no LDS)
__device__ __forceinline__ float qswap1(float v) {   // [1,0,3,2]
    return __int_as_float(__builtin_amdgcn_update_dpp(0, __float_as_int(v), 0xB1, 0xF, 0xF, true));
}
__device__ __forceinline__ float qswap2(float v) {   // [2,3,0,1]
    return __int_as_float(__builtin_amdgcn_update_dpp(0, __float_as_int(v), 0x4E, 0xF, 0xF, true));
}

__device__ __forceinline__ float sigm(float x)  { return __builtin_amdgcn_rcpf(1.f + __expf(-x)); }
__device__ __forceinline__ float tanhf_(float x){ return fmaf(2.f, __builtin_amdgcn_rcpf(1.f + __expf(-2.f*x)), -1.f); }

__global__ __launch_bounds__(NTHREADS, 2)
void lstm_seq(const int* __restrict__ tokens,
              const void* __restrict__ embed_w,
              const void* __restrict__ w_ih1,
              const void* __restrict__ w_hh1,
              const void* __restrict__ b_ih1,
              const void* __restrict__ b_hh1,
              const void* __restrict__ w_ih2,
              const void* __restrict__ w_hh2,
              const void* __restrict__ b_ih2,
              const void* __restrict__ b_hh2,
              const void* __restrict__ lin_w,
              const void* __restrict__ lin_b,
              void* __restrict__ out)
{
    // G1[v*160 + k*4 + g] = token-v pre-activation for layer-1 gate row g*40+k (biases folded)
    __shared__ float G1[NVOCAB * 4 * NH1];   // 12.8 KB
    __shared__ v4f h1b[2][10];               // h1 double-buffered (40 floats)
    __shared__ v4f h2b[2][13];               // h2 double-buffered (52 floats, 2 zero pads)

    const int tid  = threadIdx.x;
    const int wv   = tid >> 6;

    // ---- dtype sniff (uniform, deterministic) ----
    int wild = 0;
    {
        const unsigned short* ew = (const unsigned short*)embed_w;
        #pragma unroll
        for (int i = 0; i < 64; ++i) {
            int ex = (ew[i] >> 7) & 0xFF;
            wild += (ex >= 130);
        }
    }
    const int isf32 = (wild > 0) ? 1 : 0;

    // ---------------- prologue: G1 table + zero h buffers ----------------
    for (int idx = tid; idx < NVOCAB * 4 * NH1; idx += NTHREADS) {
        int v   = idx / 160;
        int rem = idx - v * 160;
        int k   = rem >> 2;
        int g   = rem & 3;
        int row = g * NH1 + k;
        float acc = ldw(b_ih1, row, isf32) + ldw(b_hh1, row, isf32);
        for (int e = 0; e < NEMBED; ++e)
            acc += ldw(embed_w, v*NEMBED + e, isf32) * ldw(w_ih1, row*NEMBED + e, isf32);
        G1[idx] = acc;
    }
    {
        v4f z; z[0]=0.f; z[1]=0.f; z[2]=0.f; z[3]=0.f;
        if (tid < 10) { h1b[0][tid] = z; h1b[1][tid] = z; }
        else if (tid < 23) { h2b[0][tid-10] = z; h2b[1][tid-10] = z; }
    }

    // ---------------- roles ----------------
    // waves 0-2: L1 — lane = gate row (k,g), tid<160, 40 weights (20 v2f)
    // waves 3-6: L2 — l2 = tid-192, gate row (s,g), l2<200, 92 weights (46 v2f)
    // wave 7   : proj — lane<20, one vocab row, 52 weights (26 v2f)
    const int g = tid & 3;
    const int l2 = tid - 192;
    const bool a1 = (wv < 3) && tid < 160;
    const bool a2 = (wv >= 3 && wv < 7) && l2 < 200;
    const bool ap = (wv == 7) && (tid & 63) < NVOCAB;

    v2f wr[46];
    float c_st = 0.f;      // cell state (L1 or L2, lane g==0 meaningful)
    float bias2 = 0.f, lb = 0.f;
    int tok = 0;

    if (a1) {
        int k = tid >> 2;
        int row = g * NH1 + k;
        #pragma unroll
        for (int j = 0; j < 20; ++j)
            wr[j] = mk2(ldw(w_hh1, row*NH1 + 2*j, isf32), ldw(w_hh1, row*NH1 + 2*j+1, isf32));
        tok = tokens[0];
    } else if (a2) {
        int s = l2 >> 2;
        int row = g * NH2 + s;
        #pragma unroll
        for (int j = 0; j < 20; ++j)
            wr[j] = mk2(ldw(w_ih2, row*NH1 + 2*j, isf32), ldw(w_ih2, row*NH1 + 2*j+1, isf32));
        #pragma unroll
        for (int j = 0; j < 25; ++j)
            wr[20+j] = mk2(ldw(w_hh2, row*NH2 + 2*j, isf32), ldw(w_hh2, row*NH2 + 2*j+1, isf32));
        wr[45] = mk2(0.f, 0.f);
        bias2 = ldw(b_ih2, row, isf32) + ldw(b_hh2, row, isf32);
    } else if (ap) {
        int pv = tid & 63;
        #pragma unroll
        for (int j = 0; j < 25; ++j)
            wr[j] = mk2(ldw(lin_w, pv*NH2 + 2*j, isf32), ldw(lin_w, pv*NH2 + 2*j+1, isf32));
        wr[25] = mk2(0.f, 0.f);
        lb = ldw(lin_b, pv, isf32);
    }

    // activation selectors: gate g==2 is tanh, others sigmoid
    const float xsc  = (g == 2) ? 2.f : 1.f;
    const float rmul = (g == 2) ? 2.f : 1.f;
    const float radd = (g == 2) ? -1.f : 0.f;

    __hip_bfloat16* out_bf = (__hip_bfloat16*)out;
    float*          out_f  = (float*)out;

    __syncthreads();

    // ------------- pipelined main loop: one barrier per step -------------
    // iter u: L1 -> h1[u];  L2 -> h2[u-1];  proj -> out[u-2]
    for (int u = 0; u < T_SEQ + 2; ++u) {
        const int cur = u & 1, prv = cur ^ 1;

        if (wv < 3) {
            if (u < T_SEQ && a1) {
                int tokN = tokens[(u + 1 < T_SEQ) ? (u + 1) : (T_SEQ - 1)];
                v2f q0 = mk2(0.f,0.f), q1 = q0, q2 = q0, q3 = q0;
                #pragma unroll
                for (int c = 0; c < 10; c += 2) {
                    v4f h0 = h1b[prv][c];
                    v4f h1 = h1b[prv][c+1];
                    q0 = __builtin_elementwise_fma(wr[2*c  ], h0.xy, q0);
                    q1 = __builtin_elementwise_fma(wr[2*c+1], h0.zw, q1);
                    q2 = __builtin_elementwise_fma(wr[2*c+2], h1.xy, q2);
                    q3 = __builtin_elementwise_fma(wr[2*c+3], h1.zw, q3);
                }
                v2f qs = (q0 + q1) + (q2 + q3);
                float acc = qs[0] + qs[1] + G1[tok*160 + tid];
                float av  = fmaf(__builtin_amdgcn_rcpf(1.f + __expf(-acc * xsc)), rmul, radd);
                float s1 = qswap1(av);          // lane0: f
                float s2 = qswap2(av);          // lane0: g
                float s3 = qswap2(s1);          // lane0: o
                float cn = fmaf(s1, c_st, av * s2);
                c_st = cn;
                float h = s3 * tanhf_(cn);
                if (g == 0) ((float*)&h1b[cur][0])[tid >> 2] = h;
                tok = tokN;
            }
        } else if (wv < 7) {
            if (u >= 1 && u <= T_SEQ && a2) {
                v2f q0 = mk2(0.f,0.f), q1 = q0, q2 = q0, q3 = q0;
                #pragma unroll
                for (int c = 0; c < 10; c += 2) {       // x-part: h1[u-1]
                    v4f h0 = h1b[prv][c];
                    v4f h1 = h1b[prv][c+1];
                    q0 = __builtin_elementwise_fma(wr[2*c  ], h0.xy, q0);
                    q1 = __builtin_elementwise_fma(wr[2*c+1], h0.zw, q1);
                    q2 = __builtin_elementwise_fma(wr[2*c+2], h1.xy, q2);
                    q3 = __builtin_elementwise_fma(wr[2*c+3], h1.zw, q3);
                }
                #pragma unroll
                for (int c = 0; c < 13; ++c) {          // h-part: h2[u-2] (52 floats, padded)
                    v4f hv = h2b[prv][c];
                    if (c & 1) {
                        q2 = __builtin_elementwise_fma(wr[20+2*c  ], hv.xy, q2);
                        q3 = __builtin_elementwise_fma(wr[20+2*c+1], hv.zw, q3);
                    } else {
                        q0 = __builtin_elementwise_fma(wr[20+2*c  ], hv.xy, q0);
                        q1 = __builtin_elementwise_fma(wr[20+2*c+1], hv.zw, q1);
                    }
                }
                v2f qs = (q0 + q1) + (q2 + q3);
                float acc = qs[0] + qs[1] + bias2;
                float av  = fmaf(__builtin_amdgcn_rcpf(1.f + __expf(-acc * xsc)), rmul, radd);
                float s1 = qswap1(av);
                float s2 = qswap2(av);
                float s3 = qswap2(s1);
                float cn = fmaf(s1, c_st, av * s2);
                c_st = cn;
                float h = s3 * tanhf_(cn);
                if (g == 0) ((float*)&h2b[cur][0])[l2 >> 2] = h;
            }
        } else {
            if (u >= 2 && ap) {
                v2f q0 = mk2(0.f,0.f), q1 = q0, q2 = q0, q3 = q0;
                #pragma unroll
                for (int c = 0; c < 13; ++c) {          // h2[u-2]
                    v4f hv = h2b[prv][c];
                    if (c & 1) {
                        q2 = __builtin_elementwise_fma(wr[2*c  ], hv.xy, q2);
                        q3 = __builtin_elementwise_fma(wr[2*c+1], hv.zw, q3);
                    } else {
                        q0 = __builtin_elementwise_fma(wr[2*c  ], hv.xy, q0);
                        q1 = __builtin_elementwise_fma(wr[2*c+1], hv.zw, q1);
                    }
                }
                v2f qs = (q0 + q1) + (q2 + q3);
                float v = qs[0] + qs[1] + lb;
                size_t oi = (size_t)(u - 2) * NVOCAB + (tid & 63);
                if (isf32) out_f[oi] = v; else out_bf[oi] = __float2bfloat16(v);
            }
        }

        __syncthreads();
    }
}

extern "C" void kernel_launch(void* const* d_in, const int* in_sizes, int n_in,
                              void* d_out, int out_size, void* d_ws, size_t ws_size,
                              hipStream_t stream) {
    const int* tokens = (const int*)d_in[0];
    lstm_seq<<<dim3(1), dim3(NTHREADS), 0, stream>>>(
        tokens, d_in[1], d_in[2], d_in[3], d_in[4], d_in[5],
        d_in[6], d_in[7], d_in[8], d_in[9], d_in[10], d_in[11], d_out);
}

// Round 5
// 244108.618 us; speedup vs baseline: 1.7688x; 1.0881x over previous
//
#include <hip/hip_runtime.h>
#include <hip/hip_bf16.h>

#define T_SEQ 500000
#define NVOCAB 20
#define NEMBED 30
#define NH1 40
#define NH2 50
#define NTHREADS 512

typedef float v2f __attribute__((ext_vector_type(2)));
typedef float v4f __attribute__((ext_vector_type(4)));

// dtype-agnostic weight load: harness may deliver floats as f32 or bf16
__device__ __forceinline__ float ldw(const void* p, int i, int isf32) {
    if (isf32) return ((const float*)p)[i];
    return __bfloat162float(((const __hip_bfloat16*)p)[i]);
}

__device__ __forceinline__ v2f mk2(float a, float b) { v2f r; r[0] = a; r[1] = b; return r; }

// DPP quad_perm swaps (VALU pipe, no LDS)
__device__ __forceinline__ float qswap1(float v) {   // [1,0,3,2]
    return __int_as_float(__builtin_amdgcn_update_dpp(0, __float_as_int(v), 0xB1, 0xF, 0xF, true));
}
__device__ __forceinline__ float qswap2(float v) {   // [2,3,0,1]
    return __int_as_float(__builtin_amdgcn_update_dpp(0, __float_as_int(v), 0x4E, 0xF, 0xF, true));
}

__device__ __forceinline__ float tanhf_(float x){ return fmaf(2.f, __builtin_amdgcn_rcpf(1.f + __expf(-2.f*x)), -1.f); }

// named-register machinery: 46 v2f weight registers w0..w45 (SSA -> cannot go to scratch)
#define DECLW v2f w0=Z2,w1=Z2,w2=Z2,w3=Z2,w4=Z2,w5=Z2,w6=Z2,w7=Z2,w8=Z2,w9=Z2, \
 w10=Z2,w11=Z2,w12=Z2,w13=Z2,w14=Z2,w15=Z2,w16=Z2,w17=Z2,w18=Z2,w19=Z2, \
 w20=Z2,w21=Z2,w22=Z2,w23=Z2,w24=Z2,w25=Z2,w26=Z2,w27=Z2,w28=Z2,w29=Z2, \
 w30=Z2,w31=Z2,w32=Z2,w33=Z2,w34=Z2,w35=Z2,w36=Z2,w37=Z2,w38=Z2,w39=Z2, \
 w40=Z2,w41=Z2,w42=Z2,w43=Z2,w44=Z2,w45=Z2

#define LD(D,P,B,J) w##D = mk2(ldw(P,(B)+2*(J),isf32), ldw(P,(B)+2*(J)+1,isf32));

// two packed-fma lines per v4f of h, alternating accumulator pairs
#define F2(WA,WB,HV) q0 = __builtin_elementwise_fma(WA,(HV).xy,q0); q1 = __builtin_elementwise_fma(WB,(HV).zw,q1);
#define G2(WA,WB,HV) q2 = __builtin_elementwise_fma(WA,(HV).xy,q2); q3 = __builtin_elementwise_fma(WB,(HV).zw,q3);

__global__ __launch_bounds__(NTHREADS, 1)
void lstm_seq(const int* __restrict__ tokens,
              const void* __restrict__ embed_w,
              const void* __restrict__ w_ih1,
              const void* __restrict__ w_hh1,
              const void* __restrict__ b_ih1,
              const void* __restrict__ b_hh1,
              const void* __restrict__ w_ih2,
              const void* __restrict__ w_hh2,
              const void* __restrict__ b_ih2,
              const void* __restrict__ b_hh2,
              const void* __restrict__ lin_w,
              const void* __restrict__ lin_b,
              void* __restrict__ out)
{
    // G1[v*160 + k*4 + g] = token-v pre-activation for layer-1 gate row g*40+k (biases folded)
    __shared__ float G1[NVOCAB * 4 * NH1];   // 12.8 KB
    __shared__ v4f h1b[2][10];               // h1 double-buffered (40 floats)
    __shared__ v4f h2b[2][13];               // h2 double-buffered (52 floats, last 2 zero)

    const int tid = threadIdx.x;
    const int wv  = tid >> 6;

    // ---- dtype sniff (uniform, deterministic) ----
    int wild = 0;
    {
        const unsigned short* ew = (const unsigned short*)embed_w;
        #pragma unroll
        for (int i = 0; i < 64; ++i) {
            int ex = (ew[i] >> 7) & 0xFF;
            wild += (ex >= 130);
        }
    }
    const int isf32 = (wild > 0) ? 1 : 0;

    // ---------------- prologue: G1 table + zero h buffers ----------------
    for (int idx = tid; idx < NVOCAB * 4 * NH1; idx += NTHREADS) {
        int v   = idx / 160;
        int rem = idx - v * 160;
        int k   = rem >> 2;
        int g   = rem & 3;
        int row = g * NH1 + k;
        float acc = ldw(b_ih1, row, isf32) + ldw(b_hh1, row, isf32);
        for (int e = 0; e < NEMBED; ++e)
            acc += ldw(embed_w, v*NEMBED + e, isf32) * ldw(w_ih1, row*NEMBED + e, isf32);
        G1[idx] = acc;
    }
    {
        v4f z; z[0]=0.f; z[1]=0.f; z[2]=0.f; z[3]=0.f;
        if (tid < 10) { h1b[0][tid] = z; h1b[1][tid] = z; }
        else if (tid < 23) { h2b[0][tid-10] = z; h2b[1][tid-10] = z; }
    }

    // ---------------- roles ----------------
    // waves 0-2: L1 — one gate row per lane (tid<160): w0..w19 = w_hh1 row
    // waves 3-6: L2 — one gate row per lane (l2=tid-192<200): w0..w19 = w_ih2 row, w20..w44 = w_hh2 row, w45=0
    // wave 7   : proj — one vocab row per lane (<20): w0..w24 = lin_w row, w25=0
    const int g  = tid & 3;
    const int l2 = tid - 192;
    const bool a1 = (wv < 3) && tid < 160;
    const bool a2 = (wv >= 3 && wv < 7) && l2 < 200;
    const bool ap = (wv == 7) && (tid & 63) < NVOCAB;

    #define Z2 mk2(0.f,0.f)
    DECLW;
    float c_st = 0.f, bias2 = 0.f, lb = 0.f;
    int tok = 0;

    if (a1) {
        int k = tid >> 2;
        int row = g * NH1 + k;
        int b = row * NH1;
        LD(0,w_hh1,b,0) LD(1,w_hh1,b,1) LD(2,w_hh1,b,2) LD(3,w_hh1,b,3) LD(4,w_hh1,b,4)
        LD(5,w_hh1,b,5) LD(6,w_hh1,b,6) LD(7,w_hh1,b,7) LD(8,w_hh1,b,8) LD(9,w_hh1,b,9)
        LD(10,w_hh1,b,10) LD(11,w_hh1,b,11) LD(12,w_hh1,b,12) LD(13,w_hh1,b,13) LD(14,w_hh1,b,14)
        LD(15,w_hh1,b,15) LD(16,w_hh1,b,16) LD(17,w_hh1,b,17) LD(18,w_hh1,b,18) LD(19,w_hh1,b,19)
        tok = tokens[0];
    } else if (a2) {
        int s = l2 >> 2;
        int row = g * NH2 + s;
        int bx = row * NH1;
        int bh = row * NH2;
        LD(0,w_ih2,bx,0) LD(1,w_ih2,bx,1) LD(2,w_ih2,bx,2) LD(3,w_ih2,bx,3) LD(4,w_ih2,bx,4)
        LD(5,w_ih2,bx,5) LD(6,w_ih2,bx,6) LD(7,w_ih2,bx,7) LD(8,w_ih2,bx,8) LD(9,w_ih2,bx,9)
        LD(10,w_ih2,bx,10) LD(11,w_ih2,bx,11) LD(12,w_ih2,bx,12) LD(13,w_ih2,bx,13) LD(14,w_ih2,bx,14)
        LD(15,w_ih2,bx,15) LD(16,w_ih2,bx,16) LD(17,w_ih2,bx,17) LD(18,w_ih2,bx,18) LD(19,w_ih2,bx,19)
        LD(20,w_hh2,bh,0) LD(21,w_hh2,bh,1) LD(22,w_hh2,bh,2) LD(23,w_hh2,bh,3) LD(24,w_hh2,bh,4)
        LD(25,w_hh2,bh,5) LD(26,w_hh2,bh,6) LD(27,w_hh2,bh,7) LD(28,w_hh2,bh,8) LD(29,w_hh2,bh,9)
        LD(30,w_hh2,bh,10) LD(31,w_hh2,bh,11) LD(32,w_hh2,bh,12) LD(33,w_hh2,bh,13) LD(34,w_hh2,bh,14)
        LD(35,w_hh2,bh,15) LD(36,w_hh2,bh,16) LD(37,w_hh2,bh,17) LD(38,w_hh2,bh,18) LD(39,w_hh2,bh,19)
        LD(40,w_hh2,bh,20) LD(41,w_hh2,bh,21) LD(42,w_hh2,bh,22) LD(43,w_hh2,bh,23) LD(44,w_hh2,bh,24)
        bias2 = ldw(b_ih2, row, isf32) + ldw(b_hh2, row, isf32);
    } else if (ap) {
        int pv = tid & 63;
        int bp = pv * NH2;
        LD(0,lin_w,bp,0) LD(1,lin_w,bp,1) LD(2,lin_w,bp,2) LD(3,lin_w,bp,3) LD(4,lin_w,bp,4)
        LD(5,lin_w,bp,5) LD(6,lin_w,bp,6) LD(7,lin_w,bp,7) LD(8,lin_w,bp,8) LD(9,lin_w,bp,9)
        LD(10,lin_w,bp,10) LD(11,lin_w,bp,11) LD(12,lin_w,bp,12) LD(13,lin_w,bp,13) LD(14,lin_w,bp,14)
        LD(15,lin_w,bp,15) LD(16,lin_w,bp,16) LD(17,lin_w,bp,17) LD(18,lin_w,bp,18) LD(19,lin_w,bp,19)
        LD(20,lin_w,bp,20) LD(21,lin_w,bp,21) LD(22,lin_w,bp,22) LD(23,lin_w,bp,23) LD(24,lin_w,bp,24)
        lb = ldw(lin_b, pv, isf32);
    }

    // activation selectors: gate g==2 is tanh, others sigmoid
    const float xsc  = (g == 2) ? 2.f : 1.f;
    const float rmul = (g == 2) ? 2.f : 1.f;
    const float radd = (g == 2) ? -1.f : 0.f;

    __hip_bfloat16* out_bf = (__hip_bfloat16*)out;
    float*          out_f  = (float*)out;

    __syncthreads();

    // ------------- pipelined main loop: one barrier per step -------------
    // iter u: L1 -> h1[u];  L2 -> h2[u-1];  proj -> out[u-2]
    for (int u = 0; u < T_SEQ + 2; ++u) {
        const int cur = u & 1, prv = cur ^ 1;
        const v4f* H1P = (const v4f*)&h1b[prv][0];
        const v4f* H2P = (const v4f*)&h2b[prv][0];

        if (wv < 3) {
            if (u < T_SEQ && a1) {
                int tokN = tokens[(u + 1 < T_SEQ) ? (u + 1) : (T_SEQ - 1)];
                v2f q0 = Z2, q1 = Z2, q2 = Z2, q3 = Z2;
                v4f ha0=H1P[0], ha1=H1P[1], ha2=H1P[2], ha3=H1P[3], ha4=H1P[4];
                v4f ha5=H1P[5], ha6=H1P[6], ha7=H1P[7], ha8=H1P[8], ha9=H1P[9];
                F2(w0,w1,ha0) G2(w2,w3,ha1) F2(w4,w5,ha2) G2(w6,w7,ha3) F2(w8,w9,ha4)
                G2(w10,w11,ha5) F2(w12,w13,ha6) G2(w14,w15,ha7) F2(w16,w17,ha8) G2(w18,w19,ha9)
                v2f qs = (q0 + q1) + (q2 + q3);
                float acc = qs[0] + qs[1] + G1[tok*160 + tid];
                float av  = fmaf(__builtin_amdgcn_rcpf(1.f + __expf(-acc * xsc)), rmul, radd);
                float s1 = qswap1(av);
                float s2 = qswap2(av);
                float s3 = qswap2(s1);
                float cn = fmaf(s1, c_st, av * s2);
                c_st = cn;
                float h = s3 * tanhf_(cn);
                if (g == 0) ((float*)&h1b[cur][0])[tid >> 2] = h;
                tok = tokN;
            }
        } else if (wv < 7) {
            if (u >= 1 && u <= T_SEQ && a2) {
                v2f q0 = Z2, q1 = Z2, q2 = Z2, q3 = Z2;
                v4f ha0=H1P[0], ha1=H1P[1], ha2=H1P[2], ha3=H1P[3], ha4=H1P[4];
                v4f ha5=H1P[5], ha6=H1P[6], ha7=H1P[7], ha8=H1P[8], ha9=H1P[9];
                F2(w0,w1,ha0) G2(w2,w3,ha1) F2(w4,w5,ha2) G2(w6,w7,ha3) F2(w8,w9,ha4)
                G2(w10,w11,ha5) F2(w12,w13,ha6) G2(w14,w15,ha7) F2(w16,w17,ha8) G2(w18,w19,ha9)
                v4f hb0=H2P[0], hb1=H2P[1], hb2=H2P[2], hb3=H2P[3], hb4=H2P[4], hb5=H2P[5], hb6=H2P[6];
                v4f hb7=H2P[7], hb8=H2P[8], hb9=H2P[9], hb10=H2P[10], hb11=H2P[11], hb12=H2P[12];
                F2(w20,w21,hb0) G2(w22,w23,hb1) F2(w24,w25,hb2) G2(w26,w27,hb3) F2(w28,w29,hb4)
                G2(w30,w31,hb5) F2(w32,w33,hb6) G2(w34,w35,hb7) F2(w36,w37,hb8) G2(w38,w39,hb9)
                F2(w40,w41,hb10) G2(w42,w43,hb11) F2(w44,w45,hb12)
                v2f qs = (q0 + q1) + (q2 + q3);
                float acc = qs[0] + qs[1] + bias2;
                float av  = fmaf(__builtin_amdgcn_rcpf(1.f + __expf(-acc * xsc)), rmul, radd);
                float s1 = qswap1(av);
                float s2 = qswap2(av);
                float s3 = qswap2(s1);
                float cn = fmaf(s1, c_st, av * s2);
                c_st = cn;
                float h = s3 * tanhf_(cn);
                if (g == 0) ((float*)&h2b[cur][0])[l2 >> 2] = h;
            }
        } else {
            if (u >= 2 && ap) {
                v2f q0 = Z2, q1 = Z2, q2 = Z2, q3 = Z2;
                v4f hb0=H2P[0], hb1=H2P[1], hb2=H2P[2], hb3=H2P[3], hb4=H2P[4], hb5=H2P[5], hb6=H2P[6];
                v4f hb7=H2P[7], hb8=H2P[8], hb9=H2P[9], hb10=H2P[10], hb11=H2P[11], hb12=H2P[12];
                F2(w0,w1,hb0) G2(w2,w3,hb1) F2(w4,w5,hb2) G2(w6,w7,hb3) F2(w8,w9,hb4)
                G2(w10,w11,hb5) F2(w12,w13,hb6) G2(w14,w15,hb7) F2(w16,w17,hb8) G2(w18,w19,hb9)
                F2(w20,w21,hb10) G2(w22,w23,hb11) F2(w24,w25,hb12)
                v2f qs = (q0 + q1) + (q2 + q3);
                float v = qs[0] + qs[1] + lb;
                size_t oi = (size_t)(u - 2) * NVOCAB + (tid & 63);
                if (isf32) out_f[oi] = v; else out_bf[oi] = __float2bfloat16(v);
            }
        }

        __syncthreads();
    }
}

extern "C" void kernel_launch(void* const* d_in, const int* in_sizes, int n_in,
                              void* d_out, int out_size, void* d_ws, size_t ws_size,
                              hipStream_t stream) {
    const int* tokens = (const int*)d_in[0];
    lstm_seq<<<dim3(1), dim3(NTHREADS), 0, stream>>>(
        tokens, d_in[1], d_in[2], d_in[3], d_in[4], d_in[5],
        d_in[6], d_in[7], d_in[8], d_in[9], d_in[10], d_in[11], d_out);
}

// Round 6
// 218214.575 us; speedup vs baseline: 1.9787x; 1.1187x over previous
//
#include <hip/hip_runtime.h>
#include <hip/hip_bf16.h>

#define T_SEQ 500000
#define NVOCAB 20
#define NEMBED 30
#define NH1 40
#define NH2 50
#define NTHREADS 512

typedef _Float16 v2h __attribute__((ext_vector_type(2)));

// dtype-agnostic weight load: harness may deliver floats as f32 or bf16
__device__ __forceinline__ float ldw(const void* p, int i, int isf32) {
    if (isf32) return ((const float*)p)[i];
    return __bfloat162float(((const __hip_bfloat16*)p)[i]);
}

__device__ __forceinline__ v2h mkh(float a, float b) { v2h r; r[0]=(_Float16)a; r[1]=(_Float16)b; return r; }
__device__ __forceinline__ v2h u2h(unsigned u){ union { unsigned u; v2h h; } x; x.u = u; return x.h; }

// DPP quad_perm swaps (VALU pipe, no LDS)
__device__ __forceinline__ float qswap1(float v) {   // [1,0,3,2]
    return __int_as_float(__builtin_amdgcn_update_dpp(0, __float_as_int(v), 0xB1, 0xF, 0xF, true));
}
__device__ __forceinline__ float qswap2(float v) {   // [2,3,0,1]
    return __int_as_float(__builtin_amdgcn_update_dpp(0, __float_as_int(v), 0x4E, 0xF, 0xF, true));
}

__device__ __forceinline__ float tanhf_(float x){ return fmaf(2.f, __builtin_amdgcn_rcpf(1.f + __expf(-2.f*x)), -1.f); }

// 48 named v2h weight registers (SSA -> stay in VGPRs)
#define ZH mkh(0.f,0.f)
#define DECLW v2h w0=ZH,w1=ZH,w2=ZH,w3=ZH,w4=ZH,w5=ZH,w6=ZH,w7=ZH,w8=ZH,w9=ZH, \
 w10=ZH,w11=ZH,w12=ZH,w13=ZH,w14=ZH,w15=ZH,w16=ZH,w17=ZH,w18=ZH,w19=ZH, \
 w20=ZH,w21=ZH,w22=ZH,w23=ZH,w24=ZH,w25=ZH,w26=ZH,w27=ZH,w28=ZH,w29=ZH, \
 w30=ZH,w31=ZH,w32=ZH,w33=ZH,w34=ZH,w35=ZH,w36=ZH,w37=ZH,w38=ZH,w39=ZH, \
 w40=ZH,w41=ZH,w42=ZH,w43=ZH,w44=ZH,w45=ZH,w46=ZH,w47=ZH

#define LDH(D,P,B,J) w##D = mkh(ldw(P,(B)+2*(J),isf32), ldw(P,(B)+2*(J)+1,isf32));

// one packed dot: Q += W . u2h(U)   (v_dot2_f32_f16)
#define DOT(Q,W,U) Q = __builtin_amdgcn_fdot2(W, u2h(U), Q, false);

__global__ __launch_bounds__(NTHREADS, 1)
void lstm_seq(const int* __restrict__ tokens,
              const void* __restrict__ embed_w,
              const void* __restrict__ w_ih1,
              const void* __restrict__ w_hh1,
              const void* __restrict__ b_ih1,
              const void* __restrict__ b_hh1,
              const void* __restrict__ w_ih2,
              const void* __restrict__ w_hh2,
              const void* __restrict__ b_ih2,
              const void* __restrict__ b_hh2,
              const void* __restrict__ lin_w,
              const void* __restrict__ lin_b,
              void* __restrict__ out)
{
    // G1[v*160 + k*4 + g]: token-v layer-1 pre-activation (biases + embed folded), f32
    __shared__ float G1[NVOCAB * 4 * NH1];   // 12.8 KB
    __shared__ uint4 h1p[2][5];              // h1 packed f16 (40 vals = 80 B), double-buffered
    __shared__ uint4 h2p[2][7];              // h2 packed f16 (50 vals + 6 zero pads = 112 B)

    const int tid = threadIdx.x;
    const int wv  = tid >> 6;

    // ---- dtype sniff (uniform, deterministic) ----
    int wild = 0;
    {
        const unsigned short* ew = (const unsigned short*)embed_w;
        #pragma unroll
        for (int i = 0; i < 64; ++i) {
            int ex = (ew[i] >> 7) & 0xFF;
            wild += (ex >= 130);
        }
    }
    const int isf32 = (wild > 0) ? 1 : 0;

    // ---------------- prologue: G1 table + zero h buffers ----------------
    for (int idx = tid; idx < NVOCAB * 4 * NH1; idx += NTHREADS) {
        int v   = idx / 160;
        int rem = idx - v * 160;
        int k   = rem >> 2;
        int g   = rem & 3;
        int row = g * NH1 + k;
        float acc = ldw(b_ih1, row, isf32) + ldw(b_hh1, row, isf32);
        for (int e = 0; e < NEMBED; ++e)
            acc += ldw(embed_w, v*NEMBED + e, isf32) * ldw(w_ih1, row*NEMBED + e, isf32);
        G1[idx] = acc;
    }
    {
        uint4 z = make_uint4(0u, 0u, 0u, 0u);
        if (tid < 5) { h1p[0][tid] = z; h1p[1][tid] = z; }
        if (tid < 7) { h2p[0][tid] = z; h2p[1][tid] = z; }
    }

    // ---------------- roles ----------------
    // waves 0-2: L1 — one gate row per lane (tid<160): w0..w19 = w_hh1 row (f16 pairs)
    // waves 3-6: L2 — one gate row per lane (l2<200): w0..w19 = w_ih2, w20..w47 = w_hh2 (pads 0)
    // wave 7   : proj — one vocab row per lane (<20): w0..w27 = lin_w row (pads 0)
    const int g  = tid & 3;
    const int l2 = tid - 192;
    const bool a1 = (wv < 3) && tid < 160;
    const bool a2 = (wv >= 3 && wv < 7) && l2 < 200;
    const bool ap = (wv == 7) && (tid & 63) < NVOCAB;

    DECLW;
    float c_st = 0.f, bias2 = 0.f, lb = 0.f;
    int tok = 0;

    if (a1) {
        int k = tid >> 2;
        int b = (g * NH1 + k) * NH1;
        LDH(0,w_hh1,b,0) LDH(1,w_hh1,b,1) LDH(2,w_hh1,b,2) LDH(3,w_hh1,b,3) LDH(4,w_hh1,b,4)
        LDH(5,w_hh1,b,5) LDH(6,w_hh1,b,6) LDH(7,w_hh1,b,7) LDH(8,w_hh1,b,8) LDH(9,w_hh1,b,9)
        LDH(10,w_hh1,b,10) LDH(11,w_hh1,b,11) LDH(12,w_hh1,b,12) LDH(13,w_hh1,b,13) LDH(14,w_hh1,b,14)
        LDH(15,w_hh1,b,15) LDH(16,w_hh1,b,16) LDH(17,w_hh1,b,17) LDH(18,w_hh1,b,18) LDH(19,w_hh1,b,19)
        tok = tokens[0];
    } else if (a2) {
        int s = l2 >> 2;
        int row = g * NH2 + s;
        int bx = row * NH1;
        int bh = row * NH2;
        LDH(0,w_ih2,bx,0) LDH(1,w_ih2,bx,1) LDH(2,w_ih2,bx,2) LDH(3,w_ih2,bx,3) LDH(4,w_ih2,bx,4)
        LDH(5,w_ih2,bx,5) LDH(6,w_ih2,bx,6) LDH(7,w_ih2,bx,7) LDH(8,w_ih2,bx,8) LDH(9,w_ih2,bx,9)
        LDH(10,w_ih2,bx,10) LDH(11,w_ih2,bx,11) LDH(12,w_ih2,bx,12) LDH(13,w_ih2,bx,13) LDH(14,w_ih2,bx,14)
        LDH(15,w_ih2,bx,15) LDH(16,w_ih2,bx,16) LDH(17,w_ih2,bx,17) LDH(18,w_ih2,bx,18) LDH(19,w_ih2,bx,19)
        LDH(20,w_hh2,bh,0) LDH(21,w_hh2,bh,1) LDH(22,w_hh2,bh,2) LDH(23,w_hh2,bh,3) LDH(24,w_hh2,bh,4)
        LDH(25,w_hh2,bh,5) LDH(26,w_hh2,bh,6) LDH(27,w_hh2,bh,7) LDH(28,w_hh2,bh,8) LDH(29,w_hh2,bh,9)
        LDH(30,w_hh2,bh,10) LDH(31,w_hh2,bh,11) LDH(32,w_hh2,bh,12) LDH(33,w_hh2,bh,13) LDH(34,w_hh2,bh,14)
        LDH(35,w_hh2,bh,15) LDH(36,w_hh2,bh,16) LDH(37,w_hh2,bh,17) LDH(38,w_hh2,bh,18) LDH(39,w_hh2,bh,19)
        LDH(40,w_hh2,bh,20) LDH(41,w_hh2,bh,21) LDH(42,w_hh2,bh,22) LDH(43,w_hh2,bh,23) LDH(44,w_hh2,bh,24)
        // w45..w47 stay zero (h2 pads)
        bias2 = ldw(b_ih2, row, isf32) + ldw(b_hh2, row, isf32);
    } else if (ap) {
        int pv = tid & 63;
        int bp = pv * NH2;
        LDH(0,lin_w,bp,0) LDH(1,lin_w,bp,1) LDH(2,lin_w,bp,2) LDH(3,lin_w,bp,3) LDH(4,lin_w,bp,4)
        LDH(5,lin_w,bp,5) LDH(6,lin_w,bp,6) LDH(7,lin_w,bp,7) LDH(8,lin_w,bp,8) LDH(9,lin_w,bp,9)
        LDH(10,lin_w,bp,10) LDH(11,lin_w,bp,11) LDH(12,lin_w,bp,12) LDH(13,lin_w,bp,13) LDH(14,lin_w,bp,14)
        LDH(15,lin_w,bp,15) LDH(16,lin_w,bp,16) LDH(17,lin_w,bp,17) LDH(18,lin_w,bp,18) LDH(19,lin_w,bp,19)
        LDH(20,lin_w,bp,20) LDH(21,lin_w,bp,21) LDH(22,lin_w,bp,22) LDH(23,lin_w,bp,23) LDH(24,lin_w,bp,24)
        // w25..w27 stay zero (h2 pads)
        lb = ldw(lin_b, pv, isf32);
    }

    // activation selectors: gate g==2 is tanh, others sigmoid
    const float xsc  = (g == 2) ? 2.f : 1.f;
    const float rmul = (g == 2) ? 2.f : 1.f;
    const float radd = (g == 2) ? -1.f : 0.f;

    __hip_bfloat16* out_bf = (__hip_bfloat16*)out;
    float*          out_f  = (float*)out;

    __syncthreads();

    // ------------- pipelined main loop: one barrier per step -------------
    // iter u: L1 -> h1[u];  L2 -> h2[u-1];  proj -> out[u-2]
    for (int u = 0; u < T_SEQ + 2; ++u) {
        const int cur = u & 1, prv = cur ^ 1;
        const uint4* H1U = &h1p[prv][0];
        const uint4* H2U = &h2p[prv][0];

        if (wv < 3) {
            if (u < T_SEQ && a1) {
                int tokN = tokens[(u + 1 < T_SEQ) ? (u + 1) : (T_SEQ - 1)];
                uint4 A0=H1U[0], A1=H1U[1], A2=H1U[2], A3=H1U[3], A4=H1U[4];
                float q0 = G1[tok*160 + tid], q1 = 0.f, q2 = 0.f, q3 = 0.f;
                DOT(q0,w0,A0.x) DOT(q1,w1,A0.y) DOT(q2,w2,A0.z) DOT(q3,w3,A0.w)
                DOT(q0,w4,A1.x) DOT(q1,w5,A1.y) DOT(q2,w6,A1.z) DOT(q3,w7,A1.w)
                DOT(q0,w8,A2.x) DOT(q1,w9,A2.y) DOT(q2,w10,A2.z) DOT(q3,w11,A2.w)
                DOT(q0,w12,A3.x) DOT(q1,w13,A3.y) DOT(q2,w14,A3.z) DOT(q3,w15,A3.w)
                DOT(q0,w16,A4.x) DOT(q1,w17,A4.y) DOT(q2,w18,A4.z) DOT(q3,w19,A4.w)
                float acc = (q0 + q1) + (q2 + q3);
                float av  = fmaf(__builtin_amdgcn_rcpf(1.f + __expf(-acc * xsc)), rmul, radd);
                float s1 = qswap1(av);
                float s2 = qswap2(av);
                float s3 = qswap2(s1);
                float cn = fmaf(s1, c_st, av * s2);
                c_st = cn;
                float h = s3 * tanhf_(cn);
                if (g == 0) ((_Float16*)&h1p[cur][0])[tid >> 2] = (_Float16)h;
                tok = tokN;
            }
        } else if (wv < 7) {
            if (u >= 1 && u <= T_SEQ && a2) {
                uint4 A0=H1U[0], A1=H1U[1], A2=H1U[2], A3=H1U[3], A4=H1U[4];
                uint4 B0=H2U[0], B1=H2U[1], B2=H2U[2], B3=H2U[3], B4=H2U[4], B5=H2U[5], B6=H2U[6];
                float q0 = bias2, q1 = 0.f, q2 = 0.f, q3 = 0.f;
                DOT(q0,w0,A0.x) DOT(q1,w1,A0.y) DOT(q2,w2,A0.z) DOT(q3,w3,A0.w)
                DOT(q0,w4,A1.x) DOT(q1,w5,A1.y) DOT(q2,w6,A1.z) DOT(q3,w7,A1.w)
                DOT(q0,w8,A2.x) DOT(q1,w9,A2.y) DOT(q2,w10,A2.z) DOT(q3,w11,A2.w)
                DOT(q0,w12,A3.x) DOT(q1,w13,A3.y) DOT(q2,w14,A3.z) DOT(q3,w15,A3.w)
                DOT(q0,w16,A4.x) DOT(q1,w17,A4.y) DOT(q2,w18,A4.z) DOT(q3,w19,A4.w)
                DOT(q0,w20,B0.x) DOT(q1,w21,B0.y) DOT(q2,w22,B0.z) DOT(q3,w23,B0.w)
                DOT(q0,w24,B1.x) DOT(q1,w25,B1.y) DOT(q2,w26,B1.z) DOT(q3,w27,B1.w)
                DOT(q0,w28,B2.x) DOT(q1,w29,B2.y) DOT(q2,w30,B2.z) DOT(q3,w31,B2.w)
                DOT(q0,w32,B3.x) DOT(q1,w33,B3.y) DOT(q2,w34,B3.z) DOT(q3,w35,B3.w)
                DOT(q0,w36,B4.x) DOT(q1,w37,B4.y) DOT(q2,w38,B4.z) DOT(q3,w39,B4.w)
                DOT(q0,w40,B5.x) DOT(q1,w41,B5.y) DOT(q2,w42,B5.z) DOT(q3,w43,B5.w)
                DOT(q0,w44,B6.x) DOT(q1,w45,B6.y) DOT(q2,w46,B6.z) DOT(q3,w47,B6.w)
                float acc = (q0 + q1) + (q2 + q3);
                float av  = fmaf(__builtin_amdgcn_rcpf(1.f + __expf(-acc * xsc)), rmul, radd);
                float s1 = qswap1(av);
                float s2 = qswap2(av);
                float s3 = qswap2(s1);
                float cn = fmaf(s1, c_st, av * s2);
                c_st = cn;
                float h = s3 * tanhf_(cn);
                if (g == 0) ((_Float16*)&h2p[cur][0])[l2 >> 2] = (_Float16)h;
            }
        } else {
            if (u >= 2 && ap) {
                uint4 B0=H2U[0], B1=H2U[1], B2=H2U[2], B3=H2U[3], B4=H2U[4], B5=H2U[5], B6=H2U[6];
                float q0 = lb, q1 = 0.f, q2 = 0.f, q3 = 0.f;
                DOT(q0,w0,B0.x) DOT(q1,w1,B0.y) DOT(q2,w2,B0.z) DOT(q3,w3,B0.w)
                DOT(q0,w4,B1.x) DOT(q1,w5,B1.y) DOT(q2,w6,B1.z) DOT(q3,w7,B1.w)
                DOT(q0,w8,B2.x) DOT(q1,w9,B2.y) DOT(q2,w10,B2.z) DOT(q3,w11,B2.w)
                DOT(q0,w12,B3.x) DOT(q1,w13,B3.y) DOT(q2,w14,B3.z) DOT(q3,w15,B3.w)
                DOT(q0,w16,B4.x) DOT(q1,w17,B4.y) DOT(q2,w18,B4.z) DOT(q3,w19,B4.w)
                DOT(q0,w20,B5.x) DOT(q1,w21,B5.y) DOT(q2,w22,B5.z) DOT(q3,w23,B5.w)
                DOT(q0,w24,B6.x) DOT(q1,w25,B6.y) DOT(q2,w26,B6.z) DOT(q3,w27,B6.w)
                float v = (q0 + q1) + (q2 + q3);
                size_t oi = (size_t)(u - 2) * NVOCAB + (tid & 63);
                if (isf32) out_f[oi] = v; else out_bf[oi] = __float2bfloat16(v);
            }
        }

        __syncthreads();
    }
}

extern "C" void kernel_launch(void* const* d_in, const int* in_sizes, int n_in,
                              void* d_out, int out_size, void* d_ws, size_t ws_size,
                              hipStream_t stream) {
    const int* tokens = (const int*)d_in[0];
    lstm_seq<<<dim3(1), dim3(NTHREADS), 0, stream>>>(
        tokens, d_in[1], d_in[2], d_in[3], d_in[4], d_in[5],
        d_in[6], d_in[7], d_in[8], d_in[9], d_in[10], d_in[11], d_out);
}

// Round 7
// 202743.616 us; speedup vs baseline: 2.1297x; 1.0763x over previous
//
#include <hip/hip_runtime.h>
#include <hip/hip_bf16.h>

#define T_SEQ 500000
#define NVOCAB 20
#define NEMBED 30
#define NH1 40
#define NH2 50
#define NTHREADS 256

typedef _Float16 v2h __attribute__((ext_vector_type(2)));

// dtype-agnostic weight load: harness may deliver floats as f32 or bf16
__device__ __forceinline__ float ldw(const void* p, int i, int isf32) {
    if (isf32) return ((const float*)p)[i];
    return __bfloat162float(((const __hip_bfloat16*)p)[i]);
}

__device__ __forceinline__ v2h mkh(float a, float b) { v2h r; r[0]=(_Float16)a; r[1]=(_Float16)b; return r; }
__device__ __forceinline__ v2h u2h(unsigned u){ union { unsigned u; v2h h; } x; x.u = u; return x.h; }

// DPP quad_perm [1,0,3,2]: swap adjacent lane pairs (VALU pipe)
__device__ __forceinline__ float qswap1(float v) {
    return __int_as_float(__builtin_amdgcn_update_dpp(0, __float_as_int(v), 0xB1, 0xF, 0xF, true));
}

__device__ __forceinline__ float sigm(float x) { return __builtin_amdgcn_rcpf(1.f + __expf(-x)); }
__device__ __forceinline__ float tanhf_(float x){ return fmaf(2.f, __builtin_amdgcn_rcpf(1.f + __expf(-2.f*x)), -1.f); }

// 90 named v2h weight registers (SSA -> stay in VGPRs). Per-role meaning:
//  L1  : w0..19=row_i, w20..39=row_f, w40..59=row_g, w60..79=row_o   (w_hh1)
//  L2  : w0..19=xA, w20..44=hA, w45..64=xB, w65..89=hB
//  proj: w0..24=lin_w row
#define ZH mkh(0.f,0.f)
#define DECLW v2h w0=ZH,w1=ZH,w2=ZH,w3=ZH,w4=ZH,w5=ZH,w6=ZH,w7=ZH,w8=ZH,w9=ZH, \
 w10=ZH,w11=ZH,w12=ZH,w13=ZH,w14=ZH,w15=ZH,w16=ZH,w17=ZH,w18=ZH,w19=ZH, \
 w20=ZH,w21=ZH,w22=ZH,w23=ZH,w24=ZH,w25=ZH,w26=ZH,w27=ZH,w28=ZH,w29=ZH, \
 w30=ZH,w31=ZH,w32=ZH,w33=ZH,w34=ZH,w35=ZH,w36=ZH,w37=ZH,w38=ZH,w39=ZH, \
 w40=ZH,w41=ZH,w42=ZH,w43=ZH,w44=ZH,w45=ZH,w46=ZH,w47=ZH,w48=ZH,w49=ZH, \
 w50=ZH,w51=ZH,w52=ZH,w53=ZH,w54=ZH,w55=ZH,w56=ZH,w57=ZH,w58=ZH,w59=ZH, \
 w60=ZH,w61=ZH,w62=ZH,w63=ZH,w64=ZH,w65=ZH,w66=ZH,w67=ZH,w68=ZH,w69=ZH, \
 w70=ZH,w71=ZH,w72=ZH,w73=ZH,w74=ZH,w75=ZH,w76=ZH,w77=ZH,w78=ZH,w79=ZH, \
 w80=ZH,w81=ZH,w82=ZH,w83=ZH,w84=ZH,w85=ZH,w86=ZH,w87=ZH,w88=ZH,w89=ZH

#define LDH(D,P,B,J) w##D = mkh(ldw(P,(B)+2*(J),isf32), ldw(P,(B)+2*(J)+1,isf32));
#define DOT(Q,W,U) Q = __builtin_amdgcn_fdot2(W, u2h(U), Q, false);

// L1: 20 h1 components x 4 gate rows, independent chains qI/qF/qG/qO
#define L1L(M) M(w0,w20,w40,w60,AA0.x) M(w1,w21,w41,w61,AA0.y) M(w2,w22,w42,w62,AA0.z) M(w3,w23,w43,w63,AA0.w) \
 M(w4,w24,w44,w64,AA1.x) M(w5,w25,w45,w65,AA1.y) M(w6,w26,w46,w66,AA1.z) M(w7,w27,w47,w67,AA1.w) \
 M(w8,w28,w48,w68,AA2.x) M(w9,w29,w49,w69,AA2.y) M(w10,w30,w50,w70,AA2.z) M(w11,w31,w51,w71,AA2.w) \
 M(w12,w32,w52,w72,AA3.x) M(w13,w33,w53,w73,AA3.y) M(w14,w34,w54,w74,AA3.z) M(w15,w35,w55,w75,AA3.w) \
 M(w16,w36,w56,w76,AA4.x) M(w17,w37,w57,w77,AA4.y) M(w18,w38,w58,w78,AA4.z) M(w19,w39,w59,w79,AA4.w)
#define L1D(WI,WF,WG,WO,C) DOT(qI,WI,C) DOT(qF,WF,C) DOT(qG,WG,C) DOT(qO,WO,C)

// L2: x-part (h1, 20 pairs) and h-part (h2, 25 pairs), rows A/B, 3 chains each
#define XAL(M) M(0,w0,w45,AA0.x) M(1,w1,w46,AA0.y) M(2,w2,w47,AA0.z) M(0,w3,w48,AA0.w) \
 M(1,w4,w49,AA1.x) M(2,w5,w50,AA1.y) M(0,w6,w51,AA1.z) M(1,w7,w52,AA1.w) \
 M(2,w8,w53,AA2.x) M(0,w9,w54,AA2.y) M(1,w10,w55,AA2.z) M(2,w11,w56,AA2.w) \
 M(0,w12,w57,AA3.x) M(1,w13,w58,AA3.y) M(2,w14,w59,AA3.z) M(0,w15,w60,AA3.w) \
 M(1,w16,w61,AA4.x) M(2,w17,w62,AA4.y) M(0,w18,w63,AA4.z) M(1,w19,w64,AA4.w)
#define HBL(M) M(0,w20,w65,BB0.x) M(1,w21,w66,BB0.y) M(2,w22,w67,BB0.z) M(0,w23,w68,BB0.w) \
 M(1,w24,w69,BB1.x) M(2,w25,w70,BB1.y) M(0,w26,w71,BB1.z) M(1,w27,w72,BB1.w) \
 M(2,w28,w73,BB2.x) M(0,w29,w74,BB2.y) M(1,w30,w75,BB2.z) M(2,w31,w76,BB2.w) \
 M(0,w32,w77,BB3.x) M(1,w33,w78,BB3.y) M(2,w34,w79,BB3.z) M(0,w35,w80,BB3.w) \
 M(1,w36,w81,BB4.x) M(2,w37,w82,BB4.y) M(0,w38,w83,BB4.z) M(1,w39,w84,BB4.w) \
 M(2,w40,w85,BB5.x) M(0,w41,w86,BB5.y) M(1,w42,w87,BB5.z) M(2,w43,w88,BB5.w) \
 M(0,w44,w89,BB6.x)
#define L2D(c,WA,WB,C) DOT(pA##c,WA,C) DOT(pB##c,WB,C)

// proj: 25 pairs, 3 chains
#define PRL(M) M(0,w0,BB0.x) M(1,w1,BB0.y) M(2,w2,BB0.z) M(0,w3,BB0.w) \
 M(1,w4,BB1.x) M(2,w5,BB1.y) M(0,w6,BB1.z) M(1,w7,BB1.w) \
 M(2,w8,BB2.x) M(0,w9,BB2.y) M(1,w10,BB2.z) M(2,w11,BB2.w) \
 M(0,w12,BB3.x) M(1,w13,BB3.y) M(2,w14,BB3.z) M(0,w15,BB3.w) \
 M(1,w16,BB4.x) M(2,w17,BB4.y) M(0,w18,BB4.z) M(1,w19,BB4.w) \
 M(2,w20,BB5.x) M(0,w21,BB5.y) M(1,w22,BB5.z) M(2,w23,BB5.w) \
 M(0,w24,BB6.x)
#define PRD(c,W,C) DOT(pP##c,W,C)

__global__ __launch_bounds__(NTHREADS, 1)
void lstm_seq(const int* __restrict__ tokens,
              const void* __restrict__ embed_w,
              const void* __restrict__ w_ih1,
              const void* __restrict__ w_hh1,
              const void* __restrict__ b_ih1,
              const void* __restrict__ b_hh1,
              const void* __restrict__ w_ih2,
              const void* __restrict__ w_hh2,
              const void* __restrict__ b_ih2,
              const void* __restrict__ b_hh2,
              const void* __restrict__ lin_w,
              const void* __restrict__ lin_b,
              void* __restrict__ out)
{
    // G1[v*160 + k*4 + g]: layer-1 pre-activation for state k, gate g, token v (f32)
    __shared__ __align__(16) float G1[NVOCAB * 4 * NH1];   // 12.8 KB
    __shared__ uint4 h1p[2][5];   // h1 packed f16, double-buffered (40 vals)
    __shared__ uint4 h2p[2][7];   // h2 packed f16, double-buffered (50 vals + pads)

    const int tid  = threadIdx.x;
    const int wv   = tid >> 6;
    const int lane = tid & 63;

    // ---- dtype sniff (uniform, deterministic) ----
    int wild = 0;
    {
        const unsigned short* ew = (const unsigned short*)embed_w;
        #pragma unroll
        for (int i = 0; i < 64; ++i) {
            int ex = (ew[i] >> 7) & 0xFF;
            wild += (ex >= 130);
        }
    }
    const int isf32 = (wild > 0) ? 1 : 0;

    // ---------------- prologue: G1 table + zero h buffers ----------------
    for (int idx = tid; idx < NVOCAB * 4 * NH1; idx += NTHREADS) {
        int v   = idx / 160;
        int rem = idx - v * 160;
        int k   = rem >> 2;
        int g   = rem & 3;
        int row = g * NH1 + k;
        float acc = ldw(b_ih1, row, isf32) + ldw(b_hh1, row, isf32);
        for (int e = 0; e < NEMBED; ++e)
            acc += ldw(embed_w, v*NEMBED + e, isf32) * ldw(w_ih1, row*NEMBED + e, isf32);
        G1[idx] = acc;
    }
    {
        uint4 z = make_uint4(0u,0u,0u,0u);
        if (tid < 5) { h1p[0][tid] = z; h1p[1][tid] = z; }
        if (tid < 7) { h2p[0][tid] = z; h2p[1][tid] = z; }
    }

    // ---------------- roles ----------------
    // wave 0: L1, lane<40 = state k, all 4 gates in-lane
    // wave 1,2: L2, lane pair (2j,2j+1) = state s=(wv-1)*25+j; even: gates i,f; odd: g,o
    // wave 3: proj, lane<20 = vocab row
    const bool a1 = (wv == 0) && lane < NH1;
    const int  j2 = lane >> 1;
    const int  s2 = (wv - 1) * 25 + j2;
    const bool a2 = (wv == 1 || wv == 2) && j2 < 25;
    const bool ap = (wv == 3) && lane < NVOCAB;
    const int  r  = lane & 1;

    DECLW;
    float c_st = 0.f, bA = 0.f, bB = 0.f, lb = 0.f;
    int tok = 0;

    if (a1) {
        int k = lane;
        int bI = (0*NH1 + k) * NH1, bF = (1*NH1 + k) * NH1;
        int bG = (2*NH1 + k) * NH1, bO = (3*NH1 + k) * NH1;
        LDH(0,w_hh1,bI,0) LDH(1,w_hh1,bI,1) LDH(2,w_hh1,bI,2) LDH(3,w_hh1,bI,3) LDH(4,w_hh1,bI,4)
        LDH(5,w_hh1,bI,5) LDH(6,w_hh1,bI,6) LDH(7,w_hh1,bI,7) LDH(8,w_hh1,bI,8) LDH(9,w_hh1,bI,9)
        LDH(10,w_hh1,bI,10) LDH(11,w_hh1,bI,11) LDH(12,w_hh1,bI,12) LDH(13,w_hh1,bI,13) LDH(14,w_hh1,bI,14)
        LDH(15,w_hh1,bI,15) LDH(16,w_hh1,bI,16) LDH(17,w_hh1,bI,17) LDH(18,w_hh1,bI,18) LDH(19,w_hh1,bI,19)
        LDH(20,w_hh1,bF,0) LDH(21,w_hh1,bF,1) LDH(22,w_hh1,bF,2) LDH(23,w_hh1,bF,3) LDH(24,w_hh1,bF,4)
        LDH(25,w_hh1,bF,5) LDH(26,w_hh1,bF,6) LDH(27,w_hh1,bF,7) LDH(28,w_hh1,bF,8) LDH(29,w_hh1,bF,9)
        LDH(30,w_hh1,bF,10) LDH(31,w_hh1,bF,11) LDH(32,w_hh1,bF,12) LDH(33,w_hh1,bF,13) LDH(34,w_hh1,bF,14)
        LDH(35,w_hh1,bF,15) LDH(36,w_hh1,bF,16) LDH(37,w_hh1,bF,17) LDH(38,w_hh1,bF,18) LDH(39,w_hh1,bF,19)
        LDH(40,w_hh1,bG,0) LDH(41,w_hh1,bG,1) LDH(42,w_hh1,bG,2) LDH(43,w_hh1,bG,3) LDH(44,w_hh1,bG,4)
        LDH(45,w_hh1,bG,5) LDH(46,w_hh1,bG,6) LDH(47,w_hh1,bG,7) LDH(48,w_hh1,bG,8) LDH(49,w_hh1,bG,9)
        LDH(50,w_hh1,bG,10) LDH(51,w_hh1,bG,11) LDH(52,w_hh1,bG,12) LDH(53,w_hh1,bG,13) LDH(54,w_hh1,bG,14)
        LDH(55,w_hh1,bG,15) LDH(56,w_hh1,bG,16) LDH(57,w_hh1,bG,17) LDH(58,w_hh1,bG,18) LDH(59,w_hh1,bG,19)
        LDH(60,w_hh1,bO,0) LDH(61,w_hh1,bO,1) LDH(62,w_hh1,bO,2) LDH(63,w_hh1,bO,3) LDH(64,w_hh1,bO,4)
        LDH(65,w_hh1,bO,5) LDH(66,w_hh1,bO,6) LDH(67,w_hh1,bO,7) LDH(68,w_hh1,bO,8) LDH(69,w_hh1,bO,9)
        LDH(70,w_hh1,bO,10) LDH(71,w_hh1,bO,11) LDH(72,w_hh1,bO,12) LDH(73,w_hh1,bO,13) LDH(74,w_hh1,bO,14)
        LDH(75,w_hh1,bO,15) LDH(76,w_hh1,bO,16) LDH(77,w_hh1,bO,17) LDH(78,w_hh1,bO,18) LDH(79,w_hh1,bO,19)
        tok = tokens[0];
    } else if (a2) {
        // even lane: rows i (0*50+s), f (1*50+s); odd lane: rows g (2*50+s), o (3*50+s)
        int rA = (r ? 2*NH2 : 0) + s2;
        int rB = (r ? 3*NH2 : NH2) + s2;
        int bxA = rA * NH1, bhA = rA * NH2;
        int bxB = rB * NH1, bhB = rB * NH2;
        LDH(0,w_ih2,bxA,0) LDH(1,w_ih2,bxA,1) LDH(2,w_ih2,bxA,2) LDH(3,w_ih2,bxA,3) LDH(4,w_ih2,bxA,4)
        LDH(5,w_ih2,bxA,5) LDH(6,w_ih2,bxA,6) LDH(7,w_ih2,bxA,7) LDH(8,w_ih2,bxA,8) LDH(9,w_ih2,bxA,9)
        LDH(10,w_ih2,bxA,10) LDH(11,w_ih2,bxA,11) LDH(12,w_ih2,bxA,12) LDH(13,w_ih2,bxA,13) LDH(14,w_ih2,bxA,14)
        LDH(15,w_ih2,bxA,15) LDH(16,w_ih2,bxA,16) LDH(17,w_ih2,bxA,17) LDH(18,w_ih2,bxA,18) LDH(19,w_ih2,bxA,19)
        LDH(20,w_hh2,bhA,0) LDH(21,w_hh2,bhA,1) LDH(22,w_hh2,bhA,2) LDH(23,w_hh2,bhA,3) LDH(24,w_hh2,bhA,4)
        LDH(25,w_hh2,bhA,5) LDH(26,w_hh2,bhA,6) LDH(27,w_hh2,bhA,7) LDH(28,w_hh2,bhA,8) LDH(29,w_hh2,bhA,9)
        LDH(30,w_hh2,bhA,10) LDH(31,w_hh2,bhA,11) LDH(32,w_hh2,bhA,12) LDH(33,w_hh2,bhA,13) LDH(34,w_hh2,bhA,14)
        LDH(35,w_hh2,bhA,15) LDH(36,w_hh2,bhA,16) LDH(37,w_hh2,bhA,17) LDH(38,w_hh2,bhA,18) LDH(39,w_hh2,bhA,19)
        LDH(40,w_hh2,bhA,20) LDH(41,w_hh2,bhA,21) LDH(42,w_hh2,bhA,22) LDH(43,w_hh2,bhA,23) LDH(44,w_hh2,bhA,24)
        LDH(45,w_ih2,bxB,0) LDH(46,w_ih2,bxB,1) LDH(47,w_ih2,bxB,2) LDH(48,w_ih2,bxB,3) LDH(49,w_ih2,bxB,4)
        LDH(50,w_ih2,bxB,5) LDH(51,w_ih2,bxB,6) LDH(52,w_ih2,bxB,7) LDH(53,w_ih2,bxB,8) LDH(54,w_ih2,bxB,9)
        LDH(55,w_ih2,bxB,10) LDH(56,w_ih2,bxB,11) LDH(57,w_ih2,bxB,12) LDH(58,w_ih2,bxB,13) LDH(59,w_ih2,bxB,14)
        LDH(60,w_ih2,bxB,15) LDH(61,w_ih2,bxB,16) LDH(62,w_ih2,bxB,17) LDH(63,w_ih2,bxB,18) LDH(64,w_ih2,bxB,19)
        LDH(65,w_hh2,bhB,0) LDH(66,w_hh2,bhB,1) LDH(67,w_hh2,bhB,2) LDH(68,w_hh2,bhB,3) LDH(69,w_hh2,bhB,4)
        LDH(70,w_hh2,bhB,5) LDH(71,w_hh2,bhB,6) LDH(72,w_hh2,bhB,7) LDH(73,w_hh2,bhB,8) LDH(74,w_hh2,bhB,9)
        LDH(75,w_hh2,bhB,10) LDH(76,w_hh2,bhB,11) LDH(77,w_hh2,bhB,12) LDH(78,w_hh2,bhB,13) LDH(79,w_hh2,bhB,14)
        LDH(80,w_hh2,bhB,15) LDH(81,w_hh2,bhB,16) LDH(82,w_hh2,bhB,17) LDH(83,w_hh2,bhB,18) LDH(84,w_hh2,bhB,19)
        LDH(85,w_hh2,bhB,20) LDH(86,w_hh2,bhB,21) LDH(87,w_hh2,bhB,22) LDH(88,w_hh2,bhB,23) LDH(89,w_hh2,bhB,24)
        bA = ldw(b_ih2, rA, isf32) + ldw(b_hh2, rA, isf32);
        bB = ldw(b_ih2, rB, isf32) + ldw(b_hh2, rB, isf32);
    } else if (ap) {
        int bp = lane * NH2;
        LDH(0,lin_w,bp,0) LDH(1,lin_w,bp,1) LDH(2,lin_w,bp,2) LDH(3,lin_w,bp,3) LDH(4,lin_w,bp,4)
        LDH(5,lin_w,bp,5) LDH(6,lin_w,bp,6) LDH(7,lin_w,bp,7) LDH(8,lin_w,bp,8) LDH(9,lin_w,bp,9)
        LDH(10,lin_w,bp,10) LDH(11,lin_w,bp,11) LDH(12,lin_w,bp,12) LDH(13,lin_w,bp,13) LDH(14,lin_w,bp,14)
        LDH(15,lin_w,bp,15) LDH(16,lin_w,bp,16) LDH(17,lin_w,bp,17) LDH(18,lin_w,bp,18) LDH(19,lin_w,bp,19)
        LDH(20,lin_w,bp,20) LDH(21,lin_w,bp,21) LDH(22,lin_w,bp,22) LDH(23,lin_w,bp,23) LDH(24,lin_w,bp,24)
        lb = ldw(lin_b, lane, isf32);
    }

    // L2 activation selectors: accA is tanh on odd lanes (g gate), sigmoid on even (i)
    const float xscA  = r ? 2.f : 1.f;
    const float rmulA = r ? 2.f : 1.f;
    const float raddA = r ? -1.f : 0.f;

    __hip_bfloat16* out_bf = (__hip_bfloat16*)out;
    float*          out_f  = (float*)out;

    __syncthreads();

    // ------------- pipelined main loop: one barrier per step -------------
    // iter u: L1 -> h1[u];  L2 -> h2[u-1];  proj -> out[u-2]
    for (int u = 0; u < T_SEQ + 2; ++u) {
        const int cur = u & 1, prv = cur ^ 1;
        const uint4* H1P = &h1p[prv][0];
        const uint4* H2P = &h2p[prv][0];

        if (wv == 0) {
            if (u < T_SEQ && a1) {
                int tokN = tokens[(u + 1 < T_SEQ) ? (u + 1) : (T_SEQ - 1)];
                uint4 AA0=H1P[0], AA1=H1P[1], AA2=H1P[2], AA3=H1P[3], AA4=H1P[4];
                float4 g4 = ((const float4*)G1)[tok*NH1 + lane];
                float qI = g4.x, qF = g4.y, qG = g4.z, qO = g4.w;
                L1L(L1D)
                float aI = sigm(qI);
                float aF = sigm(qF);
                float aG = tanhf_(qG);
                float aO = sigm(qO);
                float cn = fmaf(aF, c_st, aI * aG);
                c_st = cn;
                float h = aO * tanhf_(cn);
                ((_Float16*)&h1p[cur][0])[lane] = (_Float16)h;
                tok = tokN;
            }
        } else if (wv < 3) {
            if (u >= 1 && u <= T_SEQ && a2) {
                uint4 AA0=H1P[0], AA1=H1P[1], AA2=H1P[2], AA3=H1P[3], AA4=H1P[4];
                uint4 BB0=H2P[0], BB1=H2P[1], BB2=H2P[2], BB3=H2P[3], BB4=H2P[4], BB5=H2P[5], BB6=H2P[6];
                float pA0 = bA, pA1 = 0.f, pA2 = 0.f;
                float pB0 = bB, pB1 = 0.f, pB2 = 0.f;
                XAL(L2D)
                HBL(L2D)
                float accA = (pA0 + pA1) + pA2;
                float accB = (pB0 + pB1) + pB2;
                // even: aA=sig(i), aB=sig(f); odd: aA=tanh(g), aB=sig(o)
                float aA = fmaf(__builtin_amdgcn_rcpf(1.f + __expf(-accA * xscA)), rmulA, raddA);
                float aB = sigm(accB);
                float sA = qswap1(aA);   // even receives tanh(g)
                float sB = qswap1(aB);   // even receives sig(o)
                float cn = fmaf(aB, c_st, aA * sA);
                c_st = cn;
                float h = sB * tanhf_(cn);
                if (r == 0) ((_Float16*)&h2p[cur][0])[s2] = (_Float16)h;
            }
        } else {
            if (u >= 2 && ap) {
                uint4 BB0=H2P[0], BB1=H2P[1], BB2=H2P[2], BB3=H2P[3], BB4=H2P[4], BB5=H2P[5], BB6=H2P[6];
                float pP0 = lb, pP1 = 0.f, pP2 = 0.f;
                PRL(PRD)
                float v = (pP0 + pP1) + pP2;
                size_t oi = (size_t)(u - 2) * NVOCAB + lane;
                if (isf32) out_f[oi] = v; else out_bf[oi] = __float2bfloat16(v);
            }
        }

        __syncthreads();
    }
}

extern "C" void kernel_launch(void* const* d_in, const int* in_sizes, int n_in,
                              void* d_out, int out_size, void* d_ws, size_t ws_size,
                              hipStream_t stream) {
    const int* tokens = (const int*)d_in[0];
    lstm_seq<<<dim3(1), dim3(NTHREADS), 0, stream>>>(
        tokens, d_in[1], d_in[2], d_in[3], d_in[4], d_in[5],
        d_in[6], d_in[7], d_in[8], d_in[9], d_in[10], d_in[11], d_out);
}